// Round 4
// baseline (4434.822 us; speedup 1.0000x reference)
//
#include <hip/hip_runtime.h>
#include <cmath>

constexpr int  Bn  = 32, Tn = 512, NIn = 128, Hn = 1024;
constexpr long long TH  = (long long)Tn * Hn;    // 524288
constexpr long long BTH = (long long)Bn * TH;    // 16777216
constexpr float DTc  = 0.042f;
constexpr float UDEC = 1.0f - 1.0f * 1.0f * DTc; // R*C*dt leak
constexpr float HARM = 512.0f;                   // n_hid * p
constexpr float SPIK = 512.0f;                   // n_hid - harmonic

typedef __attribute__((ext_vector_type(8))) short short8;   // 8 bf16 (4 VGPRs)
typedef __attribute__((ext_vector_type(4))) float floatx4;  // MFMA C/D

__device__ inline unsigned short bf16_rne(float x) {
    unsigned u = __builtin_bit_cast(unsigned, x);
    u += 0x7FFFu + ((u >> 16) & 1u);
    return (unsigned short)(u >> 16);
}
__device__ inline float bf16_f(unsigned short h) {
    unsigned u = (unsigned)h << 16;
    return __builtin_bit_cast(float, u);
}

// Per-b-group arrival counters, monotonic (64 blocks each bump once per step).
__device__ unsigned g_ctr[4 * 64];

__global__ void init_ctr() {
    if (threadIdx.x < 4)
        __hip_atomic_store(&g_ctr[threadIdx.x * 64], 0u,
                           __ATOMIC_RELAXED, __HIP_MEMORY_SCOPE_AGENT);
}

// ---------------------------------------------------------------------------
// pre[row, col] = x[row, :] @ x2h[:, col] + bias[col]  (unchanged, verified)
// ---------------------------------------------------------------------------
__global__ __launch_bounds__(256) void pre_gemm(const float* __restrict__ x,
                                                const float* __restrict__ x2h,
                                                const float* __restrict__ bias,
                                                float* __restrict__ pre) {
    __shared__ float xs[64 * 128];   // [row][k]
    __shared__ float ws[128 * 64];   // [k][col]
    const int tid = threadIdx.x;
    const int rb  = blockIdx.y * 64;
    const int cb  = blockIdx.x * 64;

#pragma unroll
    for (int i = 0; i < 8; ++i) {
        int idx = i * 1024 + tid * 4;
        int r = idx >> 7, k = idx & 127;
        *(float4*)(&xs[r * 128 + k]) =
            *(const float4*)(&x[(long long)(rb + r) * NIn + k]);
    }
#pragma unroll
    for (int i = 0; i < 8; ++i) {
        int idx = i * 1024 + tid * 4;
        int k = idx >> 6, c = idx & 63;
        *(float4*)(&ws[k * 64 + c]) =
            *(const float4*)(&x2h[(long long)k * Hn + cb + c]);
    }
    __syncthreads();

    const int tx = tid & 15, ty = tid >> 4;
    const int r0 = ty * 4, c0 = tx * 4;
    float acc[4][4] = {};
#pragma unroll 4
    for (int k = 0; k < 128; ++k) {
        float4 bv = *(const float4*)(&ws[k * 64 + c0]);
        float a0 = xs[(r0 + 0) * 128 + k];
        float a1 = xs[(r0 + 1) * 128 + k];
        float a2 = xs[(r0 + 2) * 128 + k];
        float a3 = xs[(r0 + 3) * 128 + k];
        acc[0][0] += a0 * bv.x; acc[0][1] += a0 * bv.y; acc[0][2] += a0 * bv.z; acc[0][3] += a0 * bv.w;
        acc[1][0] += a1 * bv.x; acc[1][1] += a1 * bv.y; acc[1][2] += a1 * bv.z; acc[1][3] += a1 * bv.w;
        acc[2][0] += a2 * bv.x; acc[2][1] += a2 * bv.y; acc[2][2] += a2 * bv.z; acc[2][3] += a2 * bv.w;
        acc[3][0] += a3 * bv.x; acc[3][1] += a3 * bv.y; acc[3][2] += a3 * bv.z; acc[3][3] += a3 * bv.w;
    }
    float4 bb = *(const float4*)(&bias[cb + c0]);
#pragma unroll
    for (int i = 0; i < 4; ++i) {
        float4 o;
        o.x = acc[i][0] + bb.x; o.y = acc[i][1] + bb.y;
        o.z = acc[i][2] + bb.z; o.w = acc[i][3] + bb.w;
        *(float4*)(&pre[(long long)(rb + r0 + i) * Hn + cb + c0]) = o;
    }
}

// ---------------------------------------------------------------------------
// Persistent recurrence kernel, MFMA edition.
// 256 blocks = 4 b-groups x 64 h-groups; block tile = 8 batches x 16 cols.
// Matmul [8x1024]x[1024x16] via 16x16x32 bf16 MFMA, split-precision
// (hi/lo bf16): A_hi*B_hi + A_lo*B_hi + A_hi*B_lo ~ fp32 accuracy.
// - B (h2h slice) preloaded ONCE into VGPRs as bf16 hi/lo frags.
// - A (hy) loaded per step directly in fragment order via sc1 dword loads.
// - 4 waves k-split (K=256 each), LDS reduction, wave0 lanes0-31 epilogue.
// A-frag layout: lane holds A[m=lane&15][k=(lane>>4)*8+j]; rows 8-15 are pad
// (clamped duplicates of 0-7; D rows 8-15 discarded). D: col=lane&15,
// row=(lane>>4)*4+reg.
// ---------------------------------------------------------------------------
__global__ __launch_bounds__(256, 1) void ron_loop(const float* __restrict__ h2h,
                                                   const float* __restrict__ gam,
                                                   const float* __restrict__ eps,
                                                   float* __restrict__ out) {
    __shared__ float red[3 * 128];   // waves 1..3 partial C (lanes 0-31 x 4)

    const int tid  = threadIdx.x;
    const int bx   = blockIdx.x;
    const int hg   = bx & 63;        // 64 h-groups
    const int bg   = bx >> 6;        // 4 b-groups
    const int c0   = hg * 16;
    const int b0   = bg * 8;
    unsigned* ctr  = &g_ctr[bg * 64];

    const int kw   = tid >> 6;       // wave id: k-quarter
    const int lane = tid & 63;
    const int q    = lane >> 4;      // quad
    const int n    = lane & 15;      // A-row m / B-col / D-col
    const int mrow = n & 7;          // clamped A row (pad rows dup 0-7)

    float* hy_o = out;
    float* hz_o = out + BTH;
    float* u_o  = out + 2 * BTH;     // holds pre until overwritten by u
    float* sp_o = out + 3 * BTH;

    // ---- preload B frags (hi/lo) for this wave's K-quarter, once ----
    short8 Bhi[8], Blo[8];
#pragma unroll
    for (int c = 0; c < 8; ++c) {
        short8 bh, bl;
#pragma unroll
        for (int j = 0; j < 8; ++j) {
            int k = kw * 256 + c * 32 + q * 8 + j;
            float w = h2h[(long long)k * Hn + c0 + n];
            unsigned short h = bf16_rne(w);
            bh[j] = (short)h;
            bl[j] = (short)bf16_rne(w - bf16_f(h));
        }
        Bhi[c] = bh; Blo[c] = bl;
    }

    // ---- persistent state: wave 0, lanes 0-31, 4 rows (D layout) ----
    const bool epi = (kw == 0) && (lane < 32);
    const int  er0 = (lane >> 4) * 4;          // base D-row of this lane
    const float g  = gam[c0 + n];
    const float e  = eps[c0 + n];
    float hy[4] = {0.f, 0.f, 0.f, 0.f};
    float hz[4] = {0.f, 0.f, 0.f, 0.f};
    float uu[4] = {0.f, 0.f, 0.f, 0.f};

    for (int t = 0; t < Tn; ++t) {
        // prefetch pre for the 4 owned outputs (normal cached loads)
        float pre_v[4];
        if (epi) {
#pragma unroll
            for (int r = 0; r < 4; ++r)
                pre_v[r] = u_o[(long long)(b0 + er0 + r) * TH
                               + (long long)t * Hn + (c0 + n)];
        }

        floatx4 acc = {0.f, 0.f, 0.f, 0.f};
        if (t > 0) {
            // ---- load A floats in fragment order (sc1: coherent point) ----
            const float* Abase = hy_o + (long long)(b0 + mrow) * TH
                               + (long long)(t - 1) * Hn + kw * 256 + q * 8;
            float af[8][8];
#pragma unroll
            for (int c = 0; c < 8; ++c)
#pragma unroll
                for (int j = 0; j < 8; ++j)
                    af[c][j] = __hip_atomic_load(Abase + c * 32 + j,
                                                 __ATOMIC_RELAXED,
                                                 __HIP_MEMORY_SCOPE_AGENT);
            // ---- convert (split bf16) + 3-term MFMA chains ----
            floatx4 a0 = {0.f,0.f,0.f,0.f}, a1 = {0.f,0.f,0.f,0.f},
                    a2 = {0.f,0.f,0.f,0.f};
#pragma unroll
            for (int c = 0; c < 8; ++c) {
                short8 ah, al;
#pragma unroll
                for (int j = 0; j < 8; ++j) {
                    float f = af[c][j];
                    unsigned short h = bf16_rne(f);
                    ah[j] = (short)h;
                    al[j] = (short)bf16_rne(f - bf16_f(h));
                }
                a0 = __builtin_amdgcn_mfma_f32_16x16x32_bf16(ah, Bhi[c], a0, 0, 0, 0);
                a1 = __builtin_amdgcn_mfma_f32_16x16x32_bf16(al, Bhi[c], a1, 0, 0, 0);
                a2 = __builtin_amdgcn_mfma_f32_16x16x32_bf16(ah, Blo[c], a2, 0, 0, 0);
            }
            acc = a0 + a1 + a2;
        }

        // ---- cross-wave k-split reduction (rows 0-7 live in lanes 0-31) ----
        if (kw != 0 && lane < 32)
            *(floatx4*)&red[(kw - 1) * 128 + lane * 4] = acc;
        __syncthreads();

        if (epi) {
            acc += *(const floatx4*)&red[0 * 128 + lane * 4];
            acc += *(const floatx4*)&red[1 * 128 + lane * 4];
            acc += *(const floatx4*)&red[2 * 128 + lane * 4];
#pragma unroll
            for (int r = 0; r < 4; ++r) {
                float spike = (uu[r] > 0.5f) ? 1.0f : 0.0f;
                uu[r] = (spike == 1.0f) ? 0.0f : uu[r];
                uu[r] = uu[r] * UDEC;
                float drive = tanhf(acc[r] + pre_v[r]);
                hz[r] = hz[r] + DTc * (drive - g * hy[r]
                                       - (e * (hz[r] * HARM) + uu[r] * SPIK));
                hy[r] = hy[r] + DTc * hz[r];
                const long long o = (long long)(b0 + er0 + r) * TH
                                  + (long long)t * Hn + (c0 + n);
                __hip_atomic_store(&hy_o[o], hy[r],
                                   __ATOMIC_RELAXED, __HIP_MEMORY_SCOPE_AGENT);
                hz_o[o] = hz[r];
                u_o[o]  = uu[r];
                sp_o[o] = spike;
            }
        }

        // ---- per-b-group barrier (64 blocks), monotonic counter ----
        if (t < Tn - 1) {
            __syncthreads();   // drains vmcnt -> sc1 hy stores are at L3
            if (tid == 0) {
                __hip_atomic_fetch_add(ctr, 1u,
                                       __ATOMIC_RELAXED, __HIP_MEMORY_SCOPE_AGENT);
                const unsigned target = 64u * (unsigned)(t + 1);
                while (__hip_atomic_load(ctr, __ATOMIC_RELAXED,
                                         __HIP_MEMORY_SCOPE_AGENT) < target)
                    __builtin_amdgcn_s_sleep(1);
            }
            __syncthreads();
        }
    }
}

// ---------------------------------------------------------------------------
extern "C" void kernel_launch(void* const* d_in, const int* in_sizes, int n_in,
                              void* d_out, int out_size, void* d_ws, size_t ws_size,
                              hipStream_t stream) {
    const float* x    = (const float*)d_in[0];
    const float* x2h  = (const float*)d_in[1];
    const float* h2h  = (const float*)d_in[2];
    const float* gam  = (const float*)d_in[3];
    const float* eps  = (const float*)d_in[4];
    const float* bias = (const float*)d_in[5];
    float* out = (float*)d_out;
    float* pre = out + 2 * BTH;      // park pre in the u output slot

    init_ctr<<<1, 64, 0, stream>>>();
    pre_gemm<<<dim3(16, 256), dim3(256), 0, stream>>>(x, x2h, bias, pre);

    void* args[] = {(void*)&h2h, (void*)&gam, (void*)&eps, (void*)&out};
    (void)hipLaunchCooperativeKernel((void*)ron_loop, dim3(256), dim3(256),
                                     args, 0, stream);
}